// Round 6
// baseline (605.574 us; speedup 1.0000x reference)
//
#include <hip/hip_runtime.h>
#include <math.h>

// Problem constants (B=2, H=8, S=2048, D=64)
#define BH_    16          // B*H
#define S_     2048
#define D_     64
#define QT     4           // queries per block
#define BLOCK  256
#define NEWTON_ITERS 10

typedef short bf16x8 __attribute__((ext_vector_type(8)));
typedef float f32x4  __attribute__((ext_vector_type(4)));

__device__ __forceinline__ float comp(const float4& a, int u) {
  return u == 0 ? a.x : u == 1 ? a.y : u == 2 ? a.z : a.w;
}

// Split fp32 into bf16 hi (truncated) + bf16 lo (truncated remainder).
// x ≈ hi + lo with combined ~16-bit mantissa; hi*hi'+hi*lo'+lo*hi' gives
// rel err ~2^-15 on the dot product — far inside the 7.1e-2 threshold.
// Returned packed as (hi in low 16, lo in high 16) to sidestep the
// "non-const ref to vector element" compile error from R5.
__device__ __forceinline__ unsigned bf16_split_pk(float x) {
  unsigned b = __float_as_uint(x);
  unsigned h = b >> 16;
  float hf = __uint_as_float(b & 0xFFFF0000u);
  unsigned l = __float_as_uint(x - hf) >> 16;
  return h | (l << 16);
}

// Kernel 0: split k into bf16 hi/lo planes in ws (once per launch; 512
// main-kernel blocks per head reuse it instead of re-converting 512KB each).
__global__ __launch_bounds__(256)
void k_split_kernel(const float* __restrict__ k,
                    unsigned short* __restrict__ khi,
                    unsigned short* __restrict__ klo) {
  const size_t i = ((size_t)blockIdx.x * 256 + threadIdx.x) * 4;
  float4 x = *(const float4*)(k + i);
  unsigned p0 = bf16_split_pk(x.x), p1 = bf16_split_pk(x.y);
  unsigned p2 = bf16_split_pk(x.z), p3 = bf16_split_pk(x.w);
  ushort4 h; h.x = (unsigned short)(p0 & 0xFFFF); h.y = (unsigned short)(p1 & 0xFFFF);
             h.z = (unsigned short)(p2 & 0xFFFF); h.w = (unsigned short)(p3 & 0xFFFF);
  ushort4 l; l.x = (unsigned short)(p0 >> 16); l.y = (unsigned short)(p1 >> 16);
             l.z = (unsigned short)(p2 >> 16); l.w = (unsigned short)(p3 >> 16);
  *(ushort4*)(khi + i) = h;
  *(ushort4*)(klo + i) = l;
}

// __launch_bounds__(256,4): cap VGPR at 128 so 4 waves/SIMD co-reside.
// R1 evidence: without it VGPR=256 + 265MB spill traffic, occupancy 12%.
__global__ __launch_bounds__(BLOCK, 4)
void entmax_attn_kernel(const float* __restrict__ q,
                        const unsigned short* __restrict__ khi,
                        const unsigned short* __restrict__ klo,
                        const float* __restrict__ v,
                        float* __restrict__ out) {
  // sc: scores -> p -> (aliased) phase-4 partial sums. 32KB.
  __shared__ float sc[QT][S_];

  const int t   = threadIdx.x;
  const int blk = blockIdx.x;
  const int bh  = blk >> 9;          // blk / (S_/QT)
  const int qt  = blk & 511;         // blk % (S_/QT)
  const size_t qoff = ((size_t)bh * S_ + (size_t)qt * QT) * D_;
  const float* qp = q + qoff;
  const unsigned short* khw = khi + (size_t)bh * S_ * D_;
  const unsigned short* klw = klo + (size_t)bh * S_ * D_;
  const float* vp = v + (size_t)bh * S_ * D_;
  float* op = out + qoff;

  const int lane = t & 63;
  const int wv   = t >> 6;          // wave id 0..3
  const int m16  = lane & 15;
  const int quad = lane >> 4;       // 0..3

  // ---- phase 1: scores via MFMA (R4 evidence: VALU-issue-bound at 67%
  // with 2048 scalar FMAs/thread; MFMA pipe was idle). 16x16x32 bf16,
  // A = q rows (only m<4 valid, rest zero), B = k rows from split planes.
  {
    // Build A fragments once: lane holds A[m=lane&15][k=quad*8+j],
    // for k-chunks {0..31, 32..63}, hi and lo planes.
    bf16x8 Ahi[2], Alo[2];
#pragma unroll
    for (int c = 0; c < 2; ++c) {
      bf16x8 h = {0,0,0,0,0,0,0,0}, l = {0,0,0,0,0,0,0,0};
      if (m16 < QT) {
        const float* qrow = qp + m16 * D_ + c * 32 + quad * 8;
#pragma unroll
        for (int j = 0; j < 8; ++j) {
          unsigned p = bf16_split_pk(qrow[j]);
          h[j] = (short)(p & 0xFFFF);
          l[j] = (short)(p >> 16);
        }
      }
      Ahi[c] = h; Alo[c] = l;
    }

    // Each wave covers 512 keys = 32 tiles of 16.
    const int keybase0 = wv * 512;
    for (int kt = 0; kt < 32; ++kt) {
      const int key = keybase0 + kt * 16 + m16;            // B row n
      const size_t boff = (size_t)key * D_ + quad * 8;     // dim offset
      bf16x8 Bh0 = *(const bf16x8*)(khw + boff);
      bf16x8 Bh1 = *(const bf16x8*)(khw + boff + 32);
      bf16x8 Bl0 = *(const bf16x8*)(klw + boff);
      bf16x8 Bl1 = *(const bf16x8*)(klw + boff + 32);
      f32x4 c = {0.f, 0.f, 0.f, 0.f};
      // cross terms first, then the dominant hi*hi
      c = __builtin_amdgcn_mfma_f32_16x16x32_bf16(Alo[0], Bh0, c, 0, 0, 0);
      c = __builtin_amdgcn_mfma_f32_16x16x32_bf16(Alo[1], Bh1, c, 0, 0, 0);
      c = __builtin_amdgcn_mfma_f32_16x16x32_bf16(Ahi[0], Bl0, c, 0, 0, 0);
      c = __builtin_amdgcn_mfma_f32_16x16x32_bf16(Ahi[1], Bl1, c, 0, 0, 0);
      c = __builtin_amdgcn_mfma_f32_16x16x32_bf16(Ahi[0], Bh0, c, 0, 0, 0);
      c = __builtin_amdgcn_mfma_f32_16x16x32_bf16(Ahi[1], Bh1, c, 0, 0, 0);
      // C/D: col(key)=lane&15, row(query)=quad*4+reg -> queries 0-3 live
      // in lanes 0-15, regs 0-3. Scale 1/8 * entmax/2 = 1/16 at store.
      if (quad == 0) {
        const int kcol = keybase0 + kt * 16 + m16;
#pragma unroll
        for (int r = 0; r < QT; ++r) sc[r][kcol] = c[r] * 0.0625f;
      }
    }
  }
  __syncthreads();

  // ---- phase 2/3: one wave per query. Row max + Newton for tau, then p.
  {
    const int wave = wv;            // query index 0..3
    float4 xv[8];                   // row cache: 32 VGPRs
#pragma unroll
    for (int i = 0; i < 8; ++i)
      xv[i] = *(const float4*)&sc[wave][lane * 4 + i * 256];

    float m = -1e30f;
#pragma unroll
    for (int i = 0; i < 8; ++i)
      m = fmaxf(m, fmaxf(fmaxf(xv[i].x, xv[i].y), fmaxf(xv[i].z, xv[i].w)));
#pragma unroll
    for (int off = 32; off >= 1; off >>= 1)
      m = fmaxf(m, __shfl_xor(m, off, 64));
#pragma unroll
    for (int i = 0; i < 8; ++i) {   // x = (z - max(z))/2, max now 0
      xv[i].x -= m; xv[i].y -= m; xv[i].z -= m; xv[i].w -= m;
    }

    // Newton on f(tau) = sum max(x - tau, 0)^2 - 1, from tau = -1 (monotone
    // from below; f is exactly quadratic once support stabilizes ->
    // quadratic convergence; 10 iters leaves tau error << fp32 roundoff).
    float tau = -1.0f;
    for (int it = 0; it < NEWTON_ITERS; ++it) {
      float s1 = 0.f, s2 = 0.f;
#pragma unroll
      for (int i = 0; i < 8; ++i) {
        float u0 = fmaxf(xv[i].x - tau, 0.f);
        float u1 = fmaxf(xv[i].y - tau, 0.f);
        float u2 = fmaxf(xv[i].z - tau, 0.f);
        float u3 = fmaxf(xv[i].w - tau, 0.f);
        s1 += (u0 + u1) + (u2 + u3);
        s2 = fmaf(u0, u0, s2); s2 = fmaf(u1, u1, s2);
        s2 = fmaf(u2, u2, s2); s2 = fmaf(u3, u3, s2);
      }
#pragma unroll
      for (int off = 32; off >= 1; off >>= 1) {
        s1 += __shfl_xor(s1, off, 64);
        s2 += __shfl_xor(s2, off, 64);
      }
      tau += (s2 - 1.0f) / (2.0f * s1);
    }

    // p = clip(x - tau, 0)^2, write back over scores
#pragma unroll
    for (int i = 0; i < 8; ++i) {
      float u0 = fmaxf(xv[i].x - tau, 0.f);
      float u1 = fmaxf(xv[i].y - tau, 0.f);
      float u2 = fmaxf(xv[i].z - tau, 0.f);
      float u3 = fmaxf(xv[i].w - tau, 0.f);
      float4 r; r.x = u0*u0; r.y = u1*u1; r.z = u2*u2; r.w = u3*u3;
      *(float4*)&sc[wave][lane * 4 + i * 256] = r;
    }
  }
  __syncthreads();

  // ---- phase 4: out = p @ v. 16 key-groups x 16 dim-lanes (float4 dims).
  {
    const int d4 = t & 15;          // float4 column within D
    const int g  = t >> 4;          // key group, 128 keys each
    // Bank derotation (R3: conflicts 1.678e7 -> 0): rotate each g's kb
    // start by 4*g so the wave's four g-groups hit disjoint bank quads.
    const int rot = (g << 2) & 127;
    const float4* v4 = (const float4*)vp;
    float4 acc0 = {0,0,0,0}, acc1 = {0,0,0,0}, acc2 = {0,0,0,0}, acc3 = {0,0,0,0};
    const int k0 = g * 128;
#pragma unroll 2
    for (int kb = 0; kb < 128; kb += 4) {
      const int kk = k0 + ((kb + rot) & 127);
      float4 p0 = *(const float4*)&sc[0][kk];
      float4 p1 = *(const float4*)&sc[1][kk];
      float4 p2 = *(const float4*)&sc[2][kk];
      float4 p3 = *(const float4*)&sc[3][kk];
      // entmax rows are sparse: skip 4-key blocks with zero support (exact).
      float ssum = (p0.x + p0.y + p0.z + p0.w) + (p1.x + p1.y + p1.z + p1.w)
                 + (p2.x + p2.y + p2.z + p2.w) + (p3.x + p3.y + p3.z + p3.w);
      if (ssum > 0.f) {
#pragma unroll
        for (int u = 0; u < 4; ++u) {
          float4 vv = v4[(size_t)(kk + u) * (D_ / 4) + d4];
          float c0 = comp(p0, u), c1 = comp(p1, u), c2 = comp(p2, u), c3 = comp(p3, u);
          acc0.x = fmaf(c0, vv.x, acc0.x); acc0.y = fmaf(c0, vv.y, acc0.y);
          acc0.z = fmaf(c0, vv.z, acc0.z); acc0.w = fmaf(c0, vv.w, acc0.w);
          acc1.x = fmaf(c1, vv.x, acc1.x); acc1.y = fmaf(c1, vv.y, acc1.y);
          acc1.z = fmaf(c1, vv.z, acc1.z); acc1.w = fmaf(c1, vv.w, acc1.w);
          acc2.x = fmaf(c2, vv.x, acc2.x); acc2.y = fmaf(c2, vv.y, acc2.y);
          acc2.z = fmaf(c2, vv.z, acc2.z); acc2.w = fmaf(c2, vv.w, acc2.w);
          acc3.x = fmaf(c3, vv.x, acc3.x); acc3.y = fmaf(c3, vv.y, acc3.y);
          acc3.z = fmaf(c3, vv.z, acc3.z); acc3.w = fmaf(c3, vv.w, acc3.w);
        }
      }
    }
    __syncthreads();                 // all p reads done; safe to overwrite sc
    float* red = &sc[0][0];          // red[g][qq][d] : 16*4*64 floats = 16KB
    *(float4*)&red[(g * QT + 0) * D_ + d4 * 4] = acc0;
    *(float4*)&red[(g * QT + 1) * D_ + d4 * 4] = acc1;
    *(float4*)&red[(g * QT + 2) * D_ + d4 * 4] = acc2;
    *(float4*)&red[(g * QT + 3) * D_ + d4 * 4] = acc3;
    __syncthreads();
    // final cross-group reduction: thread -> (qq, d)
    const int qq = t >> 6, d = t & 63;
    float sum = 0.f;
#pragma unroll
    for (int gg = 0; gg < 16; ++gg) sum += red[(gg * QT + qq) * D_ + d];
    op[qq * D_ + d] = sum;
  }
}

extern "C" void kernel_launch(void* const* d_in, const int* in_sizes, int n_in,
                              void* d_out, int out_size, void* d_ws, size_t ws_size,
                              hipStream_t stream) {
  const float* q = (const float*)d_in[0];
  const float* k = (const float*)d_in[1];
  const float* v = (const float*)d_in[2];
  float* out = (float*)d_out;
  // ws layout: khi (4.19MB) | klo (4.19MB)
  const size_t nk = (size_t)BH_ * S_ * D_;        // 2,097,152 elements
  unsigned short* khi = (unsigned short*)d_ws;
  unsigned short* klo = khi + nk;
  k_split_kernel<<<dim3((unsigned)(nk / (256 * 4))), dim3(256), 0, stream>>>(k, khi, klo);
  dim3 grid(BH_ * (S_ / QT));   // 16 * 512 = 8192 blocks
  entmax_attn_kernel<<<grid, dim3(BLOCK), 0, stream>>>(q, khi, klo, v, out);
}

// Round 7
// 600.428 us; speedup vs baseline: 1.0086x; 1.0086x over previous
//
#include <hip/hip_runtime.h>
#include <math.h>

// Problem constants (B=2, H=8, S=2048, D=64)
#define BH_    16          // B*H
#define S_     2048
#define D_     64
#define QT     4           // queries per block
#define BLOCK  256
#define NEWTON_ITERS 10

typedef short bf16x8 __attribute__((ext_vector_type(8)));
typedef unsigned short u16x8 __attribute__((ext_vector_type(8)));
typedef float f32x4  __attribute__((ext_vector_type(4)));

__device__ __forceinline__ float comp(const float4& a, int u) {
  return u == 0 ? a.x : u == 1 ? a.y : u == 2 ? a.z : a.w;
}

// fp32 -> bf16 with round-to-nearest-even (3 ops).
__device__ __forceinline__ unsigned short bf16rne(float x) {
  unsigned u = __float_as_uint(x);
  u += 0x7FFFu + ((u >> 16) & 1u);
  return (unsigned short)(u >> 16);
}
__device__ __forceinline__ float bf16tof(unsigned short h) {
  return __uint_as_float((unsigned)h << 16);
}

// Split fp32 into bf16 hi (truncated) + bf16 lo (truncated remainder).
// hi*hi'+hi*lo'+lo*hi' gives rel err ~2^-15 on the dot product.
__device__ __forceinline__ unsigned bf16_split_pk(float x) {
  unsigned b = __float_as_uint(x);
  unsigned h = b >> 16;
  float hf = __uint_as_float(b & 0xFFFF0000u);
  unsigned l = __float_as_uint(x - hf) >> 16;
  return h | (l << 16);
}

// Kernel 0: split k into bf16 hi/lo planes in ws (once per launch; 512
// main-kernel blocks per head reuse it instead of re-converting 512KB each).
__global__ __launch_bounds__(256)
void k_split_kernel(const float* __restrict__ k,
                    unsigned short* __restrict__ khi,
                    unsigned short* __restrict__ klo) {
  const size_t i = ((size_t)blockIdx.x * 256 + threadIdx.x) * 4;
  float4 x = *(const float4*)(k + i);
  unsigned p0 = bf16_split_pk(x.x), p1 = bf16_split_pk(x.y);
  unsigned p2 = bf16_split_pk(x.z), p3 = bf16_split_pk(x.w);
  ushort4 h; h.x = (unsigned short)(p0 & 0xFFFF); h.y = (unsigned short)(p1 & 0xFFFF);
             h.z = (unsigned short)(p2 & 0xFFFF); h.w = (unsigned short)(p3 & 0xFFFF);
  ushort4 l; l.x = (unsigned short)(p0 >> 16); l.y = (unsigned short)(p1 >> 16);
             l.z = (unsigned short)(p2 >> 16); l.w = (unsigned short)(p3 >> 16);
  *(ushort4*)(khi + i) = h;
  *(ushort4*)(klo + i) = l;
}

// __launch_bounds__(256,8): R6 evidence — 600us pinned across 3 rounds with
// all pipes <45% busy => latency-stall-bound at 4 blocks/CU (32KB LDS cap).
// bf16 score storage halves LDS to 16KB -> 8 blocks/CU, 8 waves/SIMD.
__global__ __launch_bounds__(BLOCK, 8)
void entmax_attn_kernel(const float* __restrict__ q,
                        const unsigned short* __restrict__ khi,
                        const unsigned short* __restrict__ klo,
                        const float* __restrict__ v,
                        float* __restrict__ out) {
  // sc16: scores -> p (bf16) -> (aliased, fp32) phase-4 partials. 16KB.
  __shared__ unsigned short sc16[QT * S_];

  const int t   = threadIdx.x;
  const int blk = blockIdx.x;
  const int bh  = blk >> 9;          // blk / (S_/QT)
  const int qt  = blk & 511;         // blk % (S_/QT)
  const size_t qoff = ((size_t)bh * S_ + (size_t)qt * QT) * D_;
  const float* qp = q + qoff;
  const unsigned short* khw = khi + (size_t)bh * S_ * D_;
  const unsigned short* klw = klo + (size_t)bh * S_ * D_;
  const float* vp = v + (size_t)bh * S_ * D_;
  float* op = out + qoff;

  const int lane = t & 63;
  const int wv   = t >> 6;          // wave id 0..3
  const int m16  = lane & 15;
  const int quad = lane >> 4;       // 0..3

  // ---- phase 1: scores via split-bf16 MFMA (R4/R6: VALU off the critical
  // path; MFMA pipe nearly free). 16x16x32, A = q rows (m<4 valid).
  {
    bf16x8 Ahi[2], Alo[2];
#pragma unroll
    for (int c = 0; c < 2; ++c) {
      bf16x8 h = {0,0,0,0,0,0,0,0}, l = {0,0,0,0,0,0,0,0};
      if (m16 < QT) {
        const float* qrow = qp + m16 * D_ + c * 32 + quad * 8;
#pragma unroll
        for (int j = 0; j < 8; ++j) {
          unsigned p = bf16_split_pk(qrow[j]);
          h[j] = (short)(p & 0xFFFF);
          l[j] = (short)(p >> 16);
        }
      }
      Ahi[c] = h; Alo[c] = l;
    }

    // Each wave covers 512 keys = 32 tiles of 16.
    const int keybase0 = wv * 512;
    for (int kt = 0; kt < 32; ++kt) {
      const int key = keybase0 + kt * 16 + m16;            // B row n
      const size_t boff = (size_t)key * D_ + quad * 8;     // dim offset
      bf16x8 Bh0 = *(const bf16x8*)(khw + boff);
      bf16x8 Bh1 = *(const bf16x8*)(khw + boff + 32);
      bf16x8 Bl0 = *(const bf16x8*)(klw + boff);
      bf16x8 Bl1 = *(const bf16x8*)(klw + boff + 32);
      f32x4 c = {0.f, 0.f, 0.f, 0.f};
      c = __builtin_amdgcn_mfma_f32_16x16x32_bf16(Alo[0], Bh0, c, 0, 0, 0);
      c = __builtin_amdgcn_mfma_f32_16x16x32_bf16(Alo[1], Bh1, c, 0, 0, 0);
      c = __builtin_amdgcn_mfma_f32_16x16x32_bf16(Ahi[0], Bl0, c, 0, 0, 0);
      c = __builtin_amdgcn_mfma_f32_16x16x32_bf16(Ahi[1], Bl1, c, 0, 0, 0);
      c = __builtin_amdgcn_mfma_f32_16x16x32_bf16(Ahi[0], Bh0, c, 0, 0, 0);
      c = __builtin_amdgcn_mfma_f32_16x16x32_bf16(Ahi[1], Bh1, c, 0, 0, 0);
      // C/D: col(key)=lane&15, row(query)=quad*4+reg. Store bf16 RNE.
      if (quad == 0) {
        const int kcol = keybase0 + kt * 16 + m16;
#pragma unroll
        for (int r = 0; r < QT; ++r)
          sc16[r * S_ + kcol] = bf16rne(c[r] * 0.0625f);
      }
    }
  }
  __syncthreads();

  // ---- phase 2/3: one wave per query. Row max + Newton for tau, then p.
  {
    const unsigned short* row = sc16 + wv * S_;
    float4 xv[8];                   // row cache: 32 VGPRs
#pragma unroll
    for (int i = 0; i < 4; ++i) {   // 16B loads: positions lane*8 + i*512
      u16x8 c8 = *(const u16x8*)(row + lane * 8 + i * 512);
      xv[2*i+0].x = bf16tof(c8[0]); xv[2*i+0].y = bf16tof(c8[1]);
      xv[2*i+0].z = bf16tof(c8[2]); xv[2*i+0].w = bf16tof(c8[3]);
      xv[2*i+1].x = bf16tof(c8[4]); xv[2*i+1].y = bf16tof(c8[5]);
      xv[2*i+1].z = bf16tof(c8[6]); xv[2*i+1].w = bf16tof(c8[7]);
    }

    float m = -1e30f;
#pragma unroll
    for (int i = 0; i < 8; ++i)
      m = fmaxf(m, fmaxf(fmaxf(xv[i].x, xv[i].y), fmaxf(xv[i].z, xv[i].w)));
#pragma unroll
    for (int off = 32; off >= 1; off >>= 1)
      m = fmaxf(m, __shfl_xor(m, off, 64));
#pragma unroll
    for (int i = 0; i < 8; ++i) {   // x = (z - max(z))/2, max now 0
      xv[i].x -= m; xv[i].y -= m; xv[i].z -= m; xv[i].w -= m;
    }

    // Newton on f(tau) = sum max(x - tau, 0)^2 - 1, from tau = -1 (monotone
    // from below; quadratic convergence once support stabilizes).
    float tau = -1.0f;
    for (int it = 0; it < NEWTON_ITERS; ++it) {
      float s1 = 0.f, s2 = 0.f;
#pragma unroll
      for (int i = 0; i < 8; ++i) {
        float u0 = fmaxf(xv[i].x - tau, 0.f);
        float u1 = fmaxf(xv[i].y - tau, 0.f);
        float u2 = fmaxf(xv[i].z - tau, 0.f);
        float u3 = fmaxf(xv[i].w - tau, 0.f);
        s1 += (u0 + u1) + (u2 + u3);
        s2 = fmaf(u0, u0, s2); s2 = fmaf(u1, u1, s2);
        s2 = fmaf(u2, u2, s2); s2 = fmaf(u3, u3, s2);
      }
#pragma unroll
      for (int off = 32; off >= 1; off >>= 1) {
        s1 += __shfl_xor(s1, off, 64);
        s2 += __shfl_xor(s2, off, 64);
      }
      tau += (s2 - 1.0f) / (2.0f * s1);
    }

    // p = clip(x - tau, 0)^2 -> bf16 RNE, write back over scores
    unsigned short* wrow = sc16 + wv * S_;
#pragma unroll
    for (int i = 0; i < 4; ++i) {
      u16x8 r8;
#pragma unroll
      for (int j = 0; j < 8; ++j) {
        const float4& a = xv[2*i + (j >> 2)];
        float u = fmaxf(comp(a, j & 3) - tau, 0.f);
        r8[j] = bf16rne(u * u);
      }
      *(u16x8*)(wrow + lane * 8 + i * 512) = r8;
    }
  }
  __syncthreads();

  // ---- phase 4: out = p @ v. 16 key-groups x 16 dim-lanes (float4 dims).
  {
    const int d4 = t & 15;          // float4 column within D
    const int g  = t >> 4;          // key group, 128 keys each
    // Bank derotation (R3): rotate each g's kb start by 4*g. In 2-byte
    // units the 16 groups' 8B reads land on disjoint bank pairs {2g,2g+1}.
    const int rot = (g << 2) & 127;
    const float4* v4 = (const float4*)vp;
    float4 acc0 = {0,0,0,0}, acc1 = {0,0,0,0}, acc2 = {0,0,0,0}, acc3 = {0,0,0,0};
    const int k0 = g * 128;
#pragma unroll 2
    for (int kb = 0; kb < 128; kb += 4) {
      const int kk = k0 + ((kb + rot) & 127);
      ushort4 r0 = *(const ushort4*)&sc16[0 * S_ + kk];
      ushort4 r1 = *(const ushort4*)&sc16[1 * S_ + kk];
      ushort4 r2 = *(const ushort4*)&sc16[2 * S_ + kk];
      ushort4 r3 = *(const ushort4*)&sc16[3 * S_ + kk];
      float4 p0; p0.x = bf16tof(r0.x); p0.y = bf16tof(r0.y); p0.z = bf16tof(r0.z); p0.w = bf16tof(r0.w);
      float4 p1; p1.x = bf16tof(r1.x); p1.y = bf16tof(r1.y); p1.z = bf16tof(r1.z); p1.w = bf16tof(r1.w);
      float4 p2; p2.x = bf16tof(r2.x); p2.y = bf16tof(r2.y); p2.z = bf16tof(r2.z); p2.w = bf16tof(r2.w);
      float4 p3; p3.x = bf16tof(r3.x); p3.y = bf16tof(r3.y); p3.z = bf16tof(r3.z); p3.w = bf16tof(r3.w);
      // entmax rows are sparse: skip 4-key blocks with zero support (exact).
      float ssum = (p0.x + p0.y + p0.z + p0.w) + (p1.x + p1.y + p1.z + p1.w)
                 + (p2.x + p2.y + p2.z + p2.w) + (p3.x + p3.y + p3.z + p3.w);
      if (ssum > 0.f) {
#pragma unroll
        for (int u = 0; u < 4; ++u) {
          float4 vv = v4[(size_t)(kk + u) * (D_ / 4) + d4];
          float c0 = comp(p0, u), c1 = comp(p1, u), c2 = comp(p2, u), c3 = comp(p3, u);
          acc0.x = fmaf(c0, vv.x, acc0.x); acc0.y = fmaf(c0, vv.y, acc0.y);
          acc0.z = fmaf(c0, vv.z, acc0.z); acc0.w = fmaf(c0, vv.w, acc0.w);
          acc1.x = fmaf(c1, vv.x, acc1.x); acc1.y = fmaf(c1, vv.y, acc1.y);
          acc1.z = fmaf(c1, vv.z, acc1.z); acc1.w = fmaf(c1, vv.w, acc1.w);
          acc2.x = fmaf(c2, vv.x, acc2.x); acc2.y = fmaf(c2, vv.y, acc2.y);
          acc2.z = fmaf(c2, vv.z, acc2.z); acc2.w = fmaf(c2, vv.w, acc2.w);
          acc3.x = fmaf(c3, vv.x, acc3.x); acc3.y = fmaf(c3, vv.y, acc3.y);
          acc3.z = fmaf(c3, vv.z, acc3.z); acc3.w = fmaf(c3, vv.w, acc3.w);
        }
      }
    }
    __syncthreads();                 // all p reads done; safe to overwrite
    float* red = (float*)sc16;       // red[g][qq][d]: 16*4*64 fp32 = 16KB
    *(float4*)&red[(g * QT + 0) * D_ + d4 * 4] = acc0;
    *(float4*)&red[(g * QT + 1) * D_ + d4 * 4] = acc1;
    *(float4*)&red[(g * QT + 2) * D_ + d4 * 4] = acc2;
    *(float4*)&red[(g * QT + 3) * D_ + d4 * 4] = acc3;
    __syncthreads();
    // final cross-group reduction: thread -> (qq, d)
    const int qq = t >> 6, d = t & 63;
    float sum = 0.f;
#pragma unroll
    for (int gg = 0; gg < 16; ++gg) sum += red[(gg * QT + qq) * D_ + d];
    op[qq * D_ + d] = sum;
  }
}

extern "C" void kernel_launch(void* const* d_in, const int* in_sizes, int n_in,
                              void* d_out, int out_size, void* d_ws, size_t ws_size,
                              hipStream_t stream) {
  const float* q = (const float*)d_in[0];
  const float* k = (const float*)d_in[1];
  const float* v = (const float*)d_in[2];
  float* out = (float*)d_out;
  // ws layout: khi (4.19MB) | klo (4.19MB)
  const size_t nk = (size_t)BH_ * S_ * D_;        // 2,097,152 elements
  unsigned short* khi = (unsigned short*)d_ws;
  unsigned short* klo = khi + nk;
  k_split_kernel<<<dim3((unsigned)(nk / (256 * 4))), dim3(256), 0, stream>>>(k, khi, klo);
  dim3 grid(BH_ * (S_ / QT));   // 16 * 512 = 8192 blocks
  entmax_attn_kernel<<<grid, dim3(BLOCK), 0, stream>>>(q, khi, klo, v, out);
}